// Round 14
// baseline (53.807 us; speedup 1.0000x reference)
//
#include <hip/hip_runtime.h>

// MinibatchDiscrimination, round 14 — SGPR-broadcast pair phase:
//   memset    : out = 0
//   K1 kA     : xpT[s][kd][i] = partial (inputs @ T)^T  (unchanged, ~7-8us)
//   K2 kB2    : xqT[kp][i][16] = log2e * fold_s xpT  (2 k's packed per 64B row)
//   K3 pairS  : out[i,k] += sum_j exp2(-L1); j-row read via s_load (uniform
//               address -> scalar pipe), zero LDS in inner loop.
//
// inputs [512,1024] f32, T [1024,500] f32, out [512,100] f32.

#define BB 512
#define FF 1024
#define KK 100
#define KD 500
#define KDP 512
#define SPLITS 8
#define FN (FF / SPLITS)   // 128 f per split
#define STEPS (FN / 16)    // 8
#define LOG2E 1.4426950408889634f
#define NKP 50             // k-pairs
#define XQROW 16           // floats per (kp, i) row: 10 used + pad to 64B

// ---------------- K1: split-K GEMM tile, transposed partial store ---------
// grid = 512 blocks (8 i x 8 kd x 8 splits), block 256, 2/CU.
__global__ __launch_bounds__(256, 2) void kA(
    const float* __restrict__ in, const float* __restrict__ T,
    float* __restrict__ xpT)
{
    __shared__ __align__(16) float smem[2112];
    float (*Ads)[68] = (float(*)[68])smem;            // [16][68]
    float (*Bds)[64] = (float(*)[64])(smem + 1088);   // [16][64]

    const int b = blockIdx.x;
    const int t = threadIdx.x;
    const int i0  = (b & 7) * 64;
    const int kd0 = ((b >> 3) & 7) * 64;
    const int s   = b >> 6;                // 0..7
    const int tk  = t & 15;
    const int ti  = t >> 4;

    float acc[4][4];
    #pragma unroll
    for (int r = 0; r < 4; ++r)
        #pragma unroll
        for (int c = 0; c < 4; ++c) acc[r][c] = 0.f;

    const int ia  = t >> 2;                // i row for A staging
    const int fqa = t & 3;                 // f-quad for A
    const int kb  = t & 63;                // kd lane for B
    const int frb = t >> 6;                // f-quad for B
    const int kbc = min(kd0 + kb, KD - 1);

    const float* inb = in + (size_t)(i0 + ia) * FF + s * FN;
    const float* Tb  = T + (size_t)(s * FN) * KD + kbc;

    float4 av = *(const float4*)&inb[fqa * 4];
    float bv0 = Tb[(size_t)(frb * 4 + 0) * KD];
    float bv1 = Tb[(size_t)(frb * 4 + 1) * KD];
    float bv2 = Tb[(size_t)(frb * 4 + 2) * KD];
    float bv3 = Tb[(size_t)(frb * 4 + 3) * KD];

    for (int step = 0; step < STEPS; ++step) {
        Ads[fqa * 4 + 0][ia] = av.x;
        Ads[fqa * 4 + 1][ia] = av.y;
        Ads[fqa * 4 + 2][ia] = av.z;
        Ads[fqa * 4 + 3][ia] = av.w;
        Bds[frb * 4 + 0][kb] = bv0;
        Bds[frb * 4 + 1][kb] = bv1;
        Bds[frb * 4 + 2][kb] = bv2;
        Bds[frb * 4 + 3][kb] = bv3;
        __syncthreads();

        if (step + 1 < STEPS) {            // prefetch next step under the FMAs
            const int fo = (step + 1) * 16;
            av  = *(const float4*)&inb[fo + fqa * 4];
            bv0 = Tb[(size_t)(fo + frb * 4 + 0) * KD];
            bv1 = Tb[(size_t)(fo + frb * 4 + 1) * KD];
            bv2 = Tb[(size_t)(fo + frb * 4 + 2) * KD];
            bv3 = Tb[(size_t)(fo + frb * 4 + 3) * KD];
        }

        #pragma unroll
        for (int f = 0; f < 16; ++f) {
            float4 a  = *(const float4*)&Ads[f][ti * 4];
            float4 bq = *(const float4*)&Bds[f][tk * 4];
            float ar[4] = {a.x, a.y, a.z, a.w};
            float br[4] = {bq.x, bq.y, bq.z, bq.w};
            #pragma unroll
            for (int r = 0; r < 4; ++r)
                #pragma unroll
                for (int c = 0; c < 4; ++c)
                    acc[r][c] = fmaf(ar[r], br[c], acc[r][c]);
        }
        __syncthreads();
    }

    #pragma unroll
    for (int c = 0; c < 4; ++c) {
        float4 v = {acc[0][c], acc[1][c], acc[2][c], acc[3][c]};
        *(float4*)&xpT[((size_t)s * KDP + kd0 + tk * 4 + c) * BB + i0 + ti * 4] = v;
    }
}

// ---------------- K2: fold + transpose into packed xqT --------------------
// xqT[kp][i][16]: c=0..9 hold log2e * x[i][2kp*5 + c].  grid 100 x 256.
__global__ __launch_bounds__(256) void kB2(
    const float* __restrict__ xpT, float* __restrict__ xqT)
{
    const int e  = blockIdx.x * 256 + threadIdx.x;   // < 25600
    const int kp = e >> 9;          // e / 512
    const int i  = e & 511;

    float v[10];
    #pragma unroll
    for (int c = 0; c < 10; ++c) {
        float a = 0.f;
        #pragma unroll
        for (int s = 0; s < SPLITS; ++s)
            a += xpT[((size_t)s * KDP + kp * 10 + c) * BB + i];
        v[c] = LOG2E * a;
    }

    float* row = xqT + ((size_t)kp * BB + i) * XQROW;
    float4 w0 = {v[0], v[1], v[2], v[3]};
    float4 w1 = {v[4], v[5], v[6], v[7]};
    float2 w2 = {v[8], v[9]};
    *(float4*)&row[0] = w0;
    *(float4*)&row[4] = w1;
    *(float2*)&row[8] = w2;
}

// ---------------- K3: pairwise exp2(-L1), SGPR-broadcast j ----------------
// grid (50 kp, 4 ip, 2 jp) = 400 blocks, block 256 (4 waves).
// Wave w: j in [jp*256 + w*64, +64). Lane: i = ip*128 + r*64 + lane, r=0..1.
// j-row loads are wave-uniform -> s_load (scalar pipe); NO LDS in inner loop.
__global__ __launch_bounds__(256) void pairS(
    const float* __restrict__ xqT, float* __restrict__ out)
{
    const int kp = __builtin_amdgcn_readfirstlane(blockIdx.x);
    const int ip = __builtin_amdgcn_readfirstlane(blockIdx.y);
    const int jp = __builtin_amdgcn_readfirstlane(blockIdx.z);
    const int t  = threadIdx.x;
    const int lane = t & 63;
    const int w    = t >> 6;

    const float* __restrict__ xk = xqT + (size_t)kp * BB * XQROW;

    // register-resident xi: 2 i-rows x 10 (2 k's x 5 d)
    float xi[2][10];
    #pragma unroll
    for (int r = 0; r < 2; ++r) {
        const float* row = xk + (size_t)(ip * 128 + r * 64 + lane) * XQROW;
        float4 a = *(const float4*)&row[0];
        float4 b = *(const float4*)&row[4];
        float2 c = *(const float2*)&row[8];
        xi[r][0] = a.x; xi[r][1] = a.y; xi[r][2] = a.z; xi[r][3] = a.w;
        xi[r][4] = b.x; xi[r][5] = b.y; xi[r][6] = b.z; xi[r][7] = b.w;
        xi[r][8] = c.x; xi[r][9] = c.y;
    }

    float a00 = 0.f, a01 = 0.f, a10 = 0.f, a11 = 0.f;   // [r][kk]
    const int j0 = jp * 256 + w * 64;
    const float* __restrict__ jrow = xk + (size_t)j0 * XQROW;

    #pragma unroll 2
    for (int jj = 0; jj < 64; ++jj) {
        // uniform address -> compiler emits s_load_dwordx8 / dwordx2
        const float* row = jrow + (size_t)jj * XQROW;
        const float b0 = row[0], b1 = row[1], b2 = row[2], b3 = row[3];
        const float b4 = row[4], b5 = row[5], b6 = row[6], b7 = row[7];
        const float b8 = row[8], b9 = row[9];

        {   // r = 0
            float aa = (fabsf(xi[0][0] - b0) + fabsf(xi[0][1] - b1))
                     + (fabsf(xi[0][2] - b2) + fabsf(xi[0][3] - b3))
                     + fabsf(xi[0][4] - b4);
            float bb = (fabsf(xi[0][5] - b5) + fabsf(xi[0][6] - b6))
                     + (fabsf(xi[0][7] - b7) + fabsf(xi[0][8] - b8))
                     + fabsf(xi[0][9] - b9);
            a00 += __builtin_amdgcn_exp2f(-aa);
            a01 += __builtin_amdgcn_exp2f(-bb);
        }
        {   // r = 1
            float aa = (fabsf(xi[1][0] - b0) + fabsf(xi[1][1] - b1))
                     + (fabsf(xi[1][2] - b2) + fabsf(xi[1][3] - b3))
                     + fabsf(xi[1][4] - b4);
            float bb = (fabsf(xi[1][5] - b5) + fabsf(xi[1][6] - b6))
                     + (fabsf(xi[1][7] - b7) + fabsf(xi[1][8] - b8))
                     + fabsf(xi[1][9] - b9);
            a10 += __builtin_amdgcn_exp2f(-aa);
            a11 += __builtin_amdgcn_exp2f(-bb);
        }
    }

    __shared__ float ps[4][128][2];
    ps[w][lane][0]      = a00;
    ps[w][lane][1]      = a01;
    ps[w][lane + 64][0] = a10;
    ps[w][lane + 64][1] = a11;
    __syncthreads();

    if (t < 256) {
        const int il = t >> 1;
        const int kk = t & 1;
        float v = (ps[0][il][kk] + ps[1][il][kk])
                + (ps[2][il][kk] + ps[3][il][kk]);
        unsafeAtomicAdd(&out[(size_t)(ip * 128 + il) * KK + kp * 2 + kk], v);
    }
}

// ---------------- last-resort fallback (ws too small) ----------------
__global__ __launch_bounds__(1024, 1) void mbd_fused(
    const float* __restrict__ in, const float* __restrict__ T, float* __restrict__ out)
{
    const int k = blockIdx.x;
    const int t = threadIdx.x;
    const int i = t & (BB - 1);
    const int h = t >> 9;

    __shared__ float xk[1024][8];

    float a0 = 0.f, a1 = 0.f, a2 = 0.f, a3 = 0.f, a4 = 0.f;
    const float4* inrow = (const float4*)(in + (size_t)i * FF + (size_t)h * 512);
    const float* Tk = T + 5 * k + (size_t)h * 512 * KD;

    for (int ff = 0; ff < 512; ff += 4) {
        float4 v = inrow[ff >> 2];
        const float* tp = Tk + (size_t)ff * KD;
        a0 = fmaf(v.x, tp[0], a0); a1 = fmaf(v.x, tp[1], a1); a2 = fmaf(v.x, tp[2], a2);
        a3 = fmaf(v.x, tp[3], a3); a4 = fmaf(v.x, tp[4], a4); tp += KD;
        a0 = fmaf(v.y, tp[0], a0); a1 = fmaf(v.y, tp[1], a1); a2 = fmaf(v.y, tp[2], a2);
        a3 = fmaf(v.y, tp[3], a3); a4 = fmaf(v.y, tp[4], a4); tp += KD;
        a0 = fmaf(v.z, tp[0], a0); a1 = fmaf(v.z, tp[1], a1); a2 = fmaf(v.z, tp[2], a2);
        a3 = fmaf(v.z, tp[3], a3); a4 = fmaf(v.z, tp[4], a4); tp += KD;
        a0 = fmaf(v.w, tp[0], a0); a1 = fmaf(v.w, tp[1], a1); a2 = fmaf(v.w, tp[2], a2);
        a3 = fmaf(v.w, tp[3], a3); a4 = fmaf(v.w, tp[4], a4);
    }
    xk[t][0] = a0; xk[t][1] = a1; xk[t][2] = a2; xk[t][3] = a3; xk[t][4] = a4;
    __syncthreads();
    if (t < BB) {
        xk[t][0] += xk[t + BB][0]; xk[t][1] += xk[t + BB][1]; xk[t][2] += xk[t + BB][2];
        xk[t][3] += xk[t + BB][3]; xk[t][4] += xk[t + BB][4];
    }
    __syncthreads();

    const int jg = t >> 9;
    const float4 xiv = *(const float4*)&xk[i][0];
    const float xi4 = xk[i][4];
    float s0 = 0.f;
    const int j0 = jg << 8;
    for (int jj = 0; jj < 256; ++jj) {
        const int j = j0 + jj;
        float4 xj = *(const float4*)&xk[j][0];
        float xj4 = xk[j][4];
        float aa = (fabsf(xiv.x - xj.x) + fabsf(xiv.y - xj.y))
                 + (fabsf(xiv.z - xj.z) + fabsf(xiv.w - xj.w)) + fabsf(xi4 - xj4);
        s0 += __builtin_amdgcn_exp2f(-1.4426950408889634f * aa);
    }
    xk[BB + i][jg] = s0;
    __syncthreads();
    if (t < BB)
        out[(size_t)t * KK + k] = xk[BB + t][0] + xk[BB + t][1];
}

// ---------------- launch ----------------
extern "C" void kernel_launch(void* const* d_in, const int* in_sizes, int n_in,
                              void* d_out, int out_size, void* d_ws, size_t ws_size,
                              hipStream_t stream) {
    const float* in = (const float*)d_in[0];   // [512, 1024]
    const float* T  = (const float*)d_in[1];   // [1024, 500]
    float* out = (float*)d_out;                // [512, 100]

    const size_t xpT_bytes = (size_t)SPLITS * KDP * BB * sizeof(float);    // 8 MiB
    const size_t xq_bytes  = (size_t)NKP * BB * XQROW * sizeof(float);     // 1.6 MiB

    if (ws_size < xpT_bytes + xq_bytes) {
        mbd_fused<<<KK, 1024, 0, stream>>>(in, T, out);
        return;
    }

    float* xpT = (float*)d_ws;
    float* xqT = (float*)((char*)d_ws + xpT_bytes);

    hipMemsetAsync(out, 0, (size_t)BB * KK * sizeof(float), stream);

    kA<<<512, 256, 0, stream>>>(in, T, xpT);
    kB2<<<100, 256, 0, stream>>>(xpT, xqT);

    dim3 g3(NKP, 4, 2);                // 400 blocks
    pairS<<<g3, 256, 0, stream>>>(xqT, out);
}

// Round 15
// 35.262 us; speedup vs baseline: 1.5259x; 1.5259x over previous
//
#include <hip/hip_runtime.h>

// MinibatchDiscrimination, round 15 — software-pipelined pair, lean scaffold:
//   K1 kA    : xpT[s][kd][i] = partial (inputs @ T)^T  (unchanged, ~7us warm)
//   K2 kB    : xT[kd][i] = log2e * sum_s xpT[s][kd][i]  (coalesced, ~1.5us)
//   K3 pairX : out[i,k] = sum_j exp2(-L1); j-loop explicitly software-
//              pipelined (register rotation), R=2 i-rows/lane, direct writes.
//
// inputs [512,1024] f32, T [1024,500] f32, out [512,100] f32.

#define BB 512
#define FF 1024
#define KK 100
#define KD 500
#define KDP 512
#define SPLITS 8
#define FN (FF / SPLITS)   // 128 f per split
#define STEPS (FN / 16)    // 8
#define LOG2E 1.4426950408889634f

// ---------------- K1: split-K GEMM tile, transposed partial store ---------
// grid = 512 blocks (8 i x 8 kd x 8 splits), block 256, 2/CU.
__global__ __launch_bounds__(256, 2) void kA(
    const float* __restrict__ in, const float* __restrict__ T,
    float* __restrict__ xpT)
{
    __shared__ __align__(16) float smem[2112];
    float (*Ads)[68] = (float(*)[68])smem;            // [16][68]
    float (*Bds)[64] = (float(*)[64])(smem + 1088);   // [16][64]

    const int b = blockIdx.x;
    const int t = threadIdx.x;
    const int i0  = (b & 7) * 64;
    const int kd0 = ((b >> 3) & 7) * 64;
    const int s   = b >> 6;                // 0..7
    const int tk  = t & 15;
    const int ti  = t >> 4;

    float acc[4][4];
    #pragma unroll
    for (int r = 0; r < 4; ++r)
        #pragma unroll
        for (int c = 0; c < 4; ++c) acc[r][c] = 0.f;

    const int ia  = t >> 2;                // i row for A staging
    const int fqa = t & 3;                 // f-quad for A
    const int kb  = t & 63;                // kd lane for B
    const int frb = t >> 6;                // f-quad for B
    const int kbc = min(kd0 + kb, KD - 1);

    const float* inb = in + (size_t)(i0 + ia) * FF + s * FN;
    const float* Tb  = T + (size_t)(s * FN) * KD + kbc;

    float4 av = *(const float4*)&inb[fqa * 4];
    float bv0 = Tb[(size_t)(frb * 4 + 0) * KD];
    float bv1 = Tb[(size_t)(frb * 4 + 1) * KD];
    float bv2 = Tb[(size_t)(frb * 4 + 2) * KD];
    float bv3 = Tb[(size_t)(frb * 4 + 3) * KD];

    for (int step = 0; step < STEPS; ++step) {
        Ads[fqa * 4 + 0][ia] = av.x;
        Ads[fqa * 4 + 1][ia] = av.y;
        Ads[fqa * 4 + 2][ia] = av.z;
        Ads[fqa * 4 + 3][ia] = av.w;
        Bds[frb * 4 + 0][kb] = bv0;
        Bds[frb * 4 + 1][kb] = bv1;
        Bds[frb * 4 + 2][kb] = bv2;
        Bds[frb * 4 + 3][kb] = bv3;
        __syncthreads();

        if (step + 1 < STEPS) {            // prefetch next step under the FMAs
            const int fo = (step + 1) * 16;
            av  = *(const float4*)&inb[fo + fqa * 4];
            bv0 = Tb[(size_t)(fo + frb * 4 + 0) * KD];
            bv1 = Tb[(size_t)(fo + frb * 4 + 1) * KD];
            bv2 = Tb[(size_t)(fo + frb * 4 + 2) * KD];
            bv3 = Tb[(size_t)(fo + frb * 4 + 3) * KD];
        }

        #pragma unroll
        for (int f = 0; f < 16; ++f) {
            float4 a  = *(const float4*)&Ads[f][ti * 4];
            float4 bq = *(const float4*)&Bds[f][tk * 4];
            float ar[4] = {a.x, a.y, a.z, a.w};
            float br[4] = {bq.x, bq.y, bq.z, bq.w};
            #pragma unroll
            for (int r = 0; r < 4; ++r)
                #pragma unroll
                for (int c = 0; c < 4; ++c)
                    acc[r][c] = fmaf(ar[r], br[c], acc[r][c]);
        }
        __syncthreads();
    }

    #pragma unroll
    for (int c = 0; c < 4; ++c) {
        float4 v = {acc[0][c], acc[1][c], acc[2][c], acc[3][c]};
        *(float4*)&xpT[((size_t)s * KDP + kd0 + tk * 4 + c) * BB + i0 + ti * 4] = v;
    }
}

// ---------------- K2: fold splits + scale, fully coalesced ---------------
// grid 256, block 256, one float4 per thread.
__global__ __launch_bounds__(256) void kB(
    const float* __restrict__ xpT, float* __restrict__ xT)
{
    const int e = blockIdx.x * 256 + threadIdx.x;    // float4 idx < 65536
    const float4* p = (const float4*)xpT;
    float4 v = p[e];
    #pragma unroll
    for (int s = 1; s < SPLITS; ++s) {
        float4 w = p[(size_t)s * (KDP * BB / 4) + e];
        v.x += w.x; v.y += w.y; v.z += w.z; v.w += w.w;
    }
    v.x *= LOG2E; v.y *= LOG2E; v.z *= LOG2E; v.w *= LOG2E;
    ((float4*)xT)[e] = v;
}

// ---------------- K3: pairwise exp2(-L1), software-pipelined --------------
// grid (100 k, 4 ip) = 400 blocks, block 512 (8 waves).
// Wave w: j in [w*64, (w+1)*64). Lane: i = ip*128 + r*64 + lane, r=0..1.
// j-values rotate through registers: load j+1 before consuming j.
__global__ __launch_bounds__(512) void pairX(
    const float* __restrict__ xT, float* __restrict__ out)
{
    const int k  = blockIdx.x;
    const int ip = blockIdx.y;
    const int t  = threadIdx.x;
    const int lane = t & 63;
    const int w    = t >> 6;

    __shared__ float xs[BB + 2][8];   // +2 pad rows: last prefetch stays in-bounds
    __shared__ float ps[8][128];      // 4 KiB wave partials

    // fill: thread t fills row j=t (5 coalesced reads from pre-folded xT)
    #pragma unroll
    for (int d = 0; d < 5; ++d)
        xs[t][d] = xT[(size_t)(k * 5 + d) * BB + t];
    __syncthreads();

    // register-resident xi, 2 i-rows per lane
    float xi[2][5];
    #pragma unroll
    for (int r = 0; r < 2; ++r) {
        const int i = ip * 128 + r * 64 + lane;
        float4 v = *(const float4*)&xs[i][0];
        xi[r][0] = v.x; xi[r][1] = v.y; xi[r][2] = v.z; xi[r][3] = v.w;
        xi[r][4] = xs[i][4];
    }

    // software-pipelined j-loop
    const int j0 = w << 6;
    float4 c4 = *(const float4*)&xs[j0][0];
    float  c1 = xs[j0][4];
    float a0 = 0.f, a1 = 0.f;         // one acc chain per i-row

    #pragma unroll 4
    for (int jj = 0; jj < 64; ++jj) {
        // prefetch j+1 (row j0+64 is pad/next-wave data, discarded)
        const int jn = j0 + jj + 1;
        float4 n4 = *(const float4*)&xs[jn][0];
        float  n1 = xs[jn][4];

        float aa0 = (fabsf(xi[0][0] - c4.x) + fabsf(xi[0][1] - c4.y))
                  + (fabsf(xi[0][2] - c4.z) + fabsf(xi[0][3] - c4.w))
                  + fabsf(xi[0][4] - c1);
        float aa1 = (fabsf(xi[1][0] - c4.x) + fabsf(xi[1][1] - c4.y))
                  + (fabsf(xi[1][2] - c4.z) + fabsf(xi[1][3] - c4.w))
                  + fabsf(xi[1][4] - c1);
        a0 += __builtin_amdgcn_exp2f(-aa0);
        a1 += __builtin_amdgcn_exp2f(-aa1);

        c4 = n4; c1 = n1;
    }

    ps[w][lane]      = a0;
    ps[w][lane + 64] = a1;
    __syncthreads();

    if (t < 128) {
        float v = ((ps[0][t] + ps[1][t]) + (ps[2][t] + ps[3][t]))
                + ((ps[4][t] + ps[5][t]) + (ps[6][t] + ps[7][t]));
        out[(size_t)(ip * 128 + t) * KK + k] = v;
    }
}

// ---------------- last-resort fallback (ws too small) ----------------
__global__ __launch_bounds__(1024, 1) void mbd_fused(
    const float* __restrict__ in, const float* __restrict__ T, float* __restrict__ out)
{
    const int k = blockIdx.x;
    const int t = threadIdx.x;
    const int i = t & (BB - 1);
    const int h = t >> 9;

    __shared__ float xk[1024][8];

    float a0 = 0.f, a1 = 0.f, a2 = 0.f, a3 = 0.f, a4 = 0.f;
    const float4* inrow = (const float4*)(in + (size_t)i * FF + (size_t)h * 512);
    const float* Tk = T + 5 * k + (size_t)h * 512 * KD;

    for (int ff = 0; ff < 512; ff += 4) {
        float4 v = inrow[ff >> 2];
        const float* tp = Tk + (size_t)ff * KD;
        a0 = fmaf(v.x, tp[0], a0); a1 = fmaf(v.x, tp[1], a1); a2 = fmaf(v.x, tp[2], a2);
        a3 = fmaf(v.x, tp[3], a3); a4 = fmaf(v.x, tp[4], a4); tp += KD;
        a0 = fmaf(v.y, tp[0], a0); a1 = fmaf(v.y, tp[1], a1); a2 = fmaf(v.y, tp[2], a2);
        a3 = fmaf(v.y, tp[3], a3); a4 = fmaf(v.y, tp[4], a4); tp += KD;
        a0 = fmaf(v.z, tp[0], a0); a1 = fmaf(v.z, tp[1], a1); a2 = fmaf(v.z, tp[2], a2);
        a3 = fmaf(v.z, tp[3], a3); a4 = fmaf(v.z, tp[4], a4); tp += KD;
        a0 = fmaf(v.w, tp[0], a0); a1 = fmaf(v.w, tp[1], a1); a2 = fmaf(v.w, tp[2], a2);
        a3 = fmaf(v.w, tp[3], a3); a4 = fmaf(v.w, tp[4], a4);
    }
    xk[t][0] = a0; xk[t][1] = a1; xk[t][2] = a2; xk[t][3] = a3; xk[t][4] = a4;
    __syncthreads();
    if (t < BB) {
        xk[t][0] += xk[t + BB][0]; xk[t][1] += xk[t + BB][1]; xk[t][2] += xk[t + BB][2];
        xk[t][3] += xk[t + BB][3]; xk[t][4] += xk[t + BB][4];
    }
    __syncthreads();

    const int jg = t >> 9;
    const float4 xiv = *(const float4*)&xk[i][0];
    const float xi4 = xk[i][4];
    float s0 = 0.f;
    const int j0 = jg << 8;
    for (int jj = 0; jj < 256; ++jj) {
        const int j = j0 + jj;
        float4 xj = *(const float4*)&xk[j][0];
        float xj4 = xk[j][4];
        float aa = (fabsf(xiv.x - xj.x) + fabsf(xiv.y - xj.y))
                 + (fabsf(xiv.z - xj.z) + fabsf(xiv.w - xj.w)) + fabsf(xi4 - xj4);
        s0 += __builtin_amdgcn_exp2f(-1.4426950408889634f * aa);
    }
    xk[BB + i][jg] = s0;
    __syncthreads();
    if (t < BB)
        out[(size_t)t * KK + k] = xk[BB + t][0] + xk[BB + t][1];
}

// ---------------- launch ----------------
extern "C" void kernel_launch(void* const* d_in, const int* in_sizes, int n_in,
                              void* d_out, int out_size, void* d_ws, size_t ws_size,
                              hipStream_t stream) {
    const float* in = (const float*)d_in[0];   // [512, 1024]
    const float* T  = (const float*)d_in[1];   // [1024, 500]
    float* out = (float*)d_out;                // [512, 100]

    const size_t xpT_bytes = (size_t)SPLITS * KDP * BB * sizeof(float);  // 8 MiB
    const size_t xT_bytes  = (size_t)KDP * BB * sizeof(float);           // 1 MiB

    if (ws_size < xpT_bytes + xT_bytes) {
        mbd_fused<<<KK, 1024, 0, stream>>>(in, T, out);
        return;
    }

    float* xpT = (float*)d_ws;
    float* xT  = (float*)((char*)d_ws + xpT_bytes);

    kA<<<512, 256, 0, stream>>>(in, T, xpT);
    kB<<<256, 256, 0, stream>>>(xpT, xT);

    dim3 g3(KK, 4);                    // 400 blocks
    pairX<<<g3, 512, 0, stream>>>(xT, out);
}